// Round 13
// baseline (2299.411 us; speedup 1.0000x reference)
//
#include <hip/hip_runtime.h>
#include <math.h>

// Problem constants
#define T_C 8
#define K_C 64
#define NB_C 16
#define D_C 512
#define H_C 512
#define B_C 512
#define NSTEP 32          // only first 32 EM steps feed the loss (ys[3:32:4])
constexpr float DT_F   = 1.0f / 64.0f;
constexpr float SQDT_F = 0.125f;

typedef unsigned short ushort_t;

// ---------------------------------------------------------------------------
// v14: v13 + explicit 8-deep named-register weight pipeline.
// v13 post-mortem: memory-rate-bound (2MB/step/CU at 24 B/cyc == 34us step);
// in-flight audit suggests latency starvation (compiler keeps ~1-2 loads
// outstanding/wave -> ~32KB/CU vs ~40KB needed). v14: p0..p7 named registers
// (static indices, rule #20) hold 8 in-flight uint4 loads per wave; each
// consume immediately reissues 8 iterations ahead; the tail of each layer
// chains into the NEXT layer/step's block 0 so the pipeline never drains
// except at barriers. 128KB in flight/CU. Values + d-order identical to
// passing v13 -> bit-identical output.
// Falls back to the bit-exact fp32 v9 kernel if workspace is too small.
// ---------------------------------------------------------------------------

__device__ __forceinline__ ushort_t f2h(float f) {
    _Float16 h = (_Float16)f;                 // v_cvt_f16_f32 (RNE)
    union { _Float16 h; ushort_t u; } v; v.h = h; return v.u;
}

typedef _Float16 half2v __attribute__((ext_vector_type(2)));

__device__ __forceinline__ float dot2f(unsigned a2, unsigned b2, float acc) {
    union { unsigned u; half2v h; } a, b;
    a.u = a2; b.u = b2;
#if __has_builtin(__builtin_amdgcn_fdot2)
    return __builtin_amdgcn_fdot2(a.h, b.h, acc, false);  // v_dot2_f32_f16
#else
    return acc + (float)a.h.x * (float)b.h.x + (float)a.h.y * (float)b.h.y;
#endif
}

__device__ __forceinline__ unsigned pkh(float a, float b) {
    return (unsigned)f2h(a) | ((unsigned)f2h(b) << 16);
}

// Prepass: per (k, layer L, net, d-oct, col) write uint4 =
//   { pkh(w[8o][c],w[8o+1][c]), pkh(w[8o+2],w[8o+3]),
//     pkh(w[8o+4],w[8o+5]),    pkh(w[8o+6],w[8o+7]) }
// Segment layout: Wq[(((k*2+L)*2+net)*64 + o)*512 + col].
__global__ __launch_bounds__(256) void cvt_kernel(
    const float* __restrict__ Wf1, const float* __restrict__ Wf2,
    const float* __restrict__ Wg1, const float* __restrict__ Wg2,
    uint4* __restrict__ Wq)
{
    for (unsigned u = blockIdx.x * 256 + threadIdx.x; u < 8388608u;
         u += 8192u * 256u) {
        unsigned col = u & 511u, o = (u >> 9) & 63u;
        unsigned net = (u >> 15) & 1u, L = (u >> 16) & 1u, k = u >> 17;
        const float* M = net ? (L ? Wg2 : Wg1) : (L ? Wf2 : Wf1);
        size_t ib = (size_t)k * 262144 + (size_t)(8 * o) * 512 + col;
        uint4 w;
        w.x = pkh(M[ib],        M[ib + 512]);
        w.y = pkh(M[ib + 1024], M[ib + 1536]);
        w.z = pkh(M[ib + 2048], M[ib + 2560]);
        w.w = pkh(M[ib + 3072], M[ib + 3584]);
        Wq[u] = w;
    }
}

// One pipeline body: consume pj (8 f16 weights), immediately reload 8 iters
// ahead (Wn), 16 fdot2 against 4 activation-row quads.
#define PIPE_BODY(j, pj)                                                     \
    {                                                                        \
        uint4 wv = pj; pj = Wn[(j) * 512];                                   \
        uint4 va = aq[(o0 + (j)) * 4 + 0];                                   \
        uint4 vb = aq[(o0 + (j)) * 4 + 1];                                   \
        uint4 vc = aq[(o0 + (j)) * 4 + 2];                                   \
        uint4 vd = aq[(o0 + (j)) * 4 + 3];                                   \
        r0 = dot2f(va.x, wv.x, r0); r1 = dot2f(va.y, wv.x, r1);              \
        r2 = dot2f(va.z, wv.x, r2); r3 = dot2f(va.w, wv.x, r3);              \
        r0 = dot2f(vb.x, wv.y, r0); r1 = dot2f(vb.y, wv.y, r1);              \
        r2 = dot2f(vb.z, wv.y, r2); r3 = dot2f(vb.w, wv.y, r3);              \
        r0 = dot2f(vc.x, wv.z, r0); r1 = dot2f(vc.y, wv.z, r1);              \
        r2 = dot2f(vc.z, wv.z, r2); r3 = dot2f(vc.w, wv.z, r3);              \
        r0 = dot2f(vd.x, wv.w, r0); r1 = dot2f(vd.y, wv.w, r1);              \
        r2 = dot2f(vd.z, wv.w, r2); r3 = dot2f(vd.w, wv.w, r3);              \
    }

// One layer: 8 outer blocks x 8 pipelined bodies. The last block's reloads
// chain into `Wnext` (next layer / next step) so the pipeline never drains.
#define PIPE_LAYER(aq_, Wcur_, Wnext_)                                       \
    {                                                                        \
        const uint4* aq = (aq_);                                             \
        for (int ob = 0; ob < 8; ++ob) {                                     \
            const uint4* Wn = ((ob < 7) ? (Wcur_) : (Wnext_))                \
                            + (((ob + 1) & 7) * 8) * 512;                    \
            const int o0 = ob * 8;                                           \
            PIPE_BODY(0, p0) PIPE_BODY(1, p1) PIPE_BODY(2, p2)               \
            PIPE_BODY(3, p3) PIPE_BODY(4, p4) PIPE_BODY(5, p5)               \
            PIPE_BODY(6, p6) PIPE_BODY(7, p7)                                \
        }                                                                    \
    }

// ---------------------------------------------------------------------------
// SDE kernel (f16, net-split, pipelined): 256 blocks, 1024 threads.
// Thread (net = tid>>9, col = tid&511) owns column `col` of net `net`.
// ---------------------------------------------------------------------------
__global__ __launch_bounds__(1024, 4) void sde_f16_kernel(
    const float* __restrict__ init_mu, const float* __restrict__ init_noise,
    const uint4* __restrict__ Wq,
    const float* __restrict__ bf1, const float* __restrict__ bf2,
    const float* __restrict__ bg1, const float* __restrict__ bg2,
    const float* __restrict__ dW, float* __restrict__ path)
{
    // Quartet-on-one-XCD swizzle: siblings share their XCD's L2 weight lines.
    const int b    = blockIdx.x;
    const int xcd  = b & 7;
    const int slot = b >> 3;              // 0..31
    const int k    = xcd * 8 + (slot >> 2);
    const int q    = slot & 3;            // row-group within k
    const int nb0  = q * 4;               // this block's 4 nb-rows

    const int tid = threadIdx.x;
    const int net = tid >> 9;             // 0 = drift(f), 1 = diffusion(g)
    const int col = tid & 511;            // this thread's output column
    const int cp  = col >> 1;             // d-pair index of this column
    const int par = col & 1;              // low/high half within the pair

    __shared__ __align__(16) unsigned ys2[256][4];  // [dpair][row] f16x2
    __shared__ __align__(16) unsigned hs2[256][4];  // drift tanh
    __shared__ __align__(16) unsigned gs2[256][4];  // diffusion tanh
    __shared__ float tmp2[4][512];                  // diffusion sigmoid g->f

    // fp32 y-state for this column x rows 0..3 lives in f-net threads.
    float y0 = 0.f, y1 = 0.f, y2 = 0.f, y3 = 0.f;
    ushort_t* ysh = (ushort_t*)&ys2[0][0];
    if (!net) {
        const float* mu = init_mu + k * 512;
        const float* nz = init_noise + (size_t)(k * 16 + nb0) * 512;
        y0 = mu[col] + 0.05f * nz[col];
        y1 = mu[col] + 0.05f * nz[512 + col];
        y2 = mu[col] + 0.05f * nz[1024 + col];
        y3 = mu[col] + 0.05f * nz[1536 + col];
        ysh[(cp * 4 + 0) * 2 + par] = f2h(y0);
        ysh[(cp * 4 + 1) * 2 + par] = f2h(y1);
        ysh[(cp * 4 + 2) * 2 + par] = f2h(y2);
        ysh[(cp * 4 + 3) * 2 + par] = f2h(y3);
    }

    // Per-net weight segments (64 uint4-rows of 512 cols per layer).
    const uint4* W1 = Wq + (((size_t)k * 2 + 0) * 2 + net) * 32768 + col;
    const uint4* W2 = Wq + (((size_t)k * 2 + 1) * 2 + net) * 32768 + col;
    const float b1 = (net ? bg1 : bf1)[k * 512 + col];
    const float b2 = (net ? bg2 : bf2)[k * 512 + col];

    ushort_t* acth = (ushort_t*)(net ? &gs2[0][0] : &hs2[0][0]);
    const uint4* yq = (const uint4*)&ys2[0][0];
    const uint4* hq = (const uint4*)(net ? &gs2[0][0] : &hs2[0][0]);

    __syncthreads();             // ys2 ready

    // Prime the 8-deep pipeline with layer-1 block 0.
    uint4 p0 = W1[0 * 512], p1 = W1[1 * 512], p2 = W1[2 * 512],
          p3 = W1[3 * 512], p4 = W1[4 * 512], p5 = W1[5 * 512],
          p6 = W1[6 * 512], p7 = W1[7 * 512];

    for (int s = 0; s < NSTEP; ++s) {
        // dW for this column's 4 rows (f net only) — lands under layer 1.
        float dw0, dw1, dw2, dw3;
        if (!net) {
            const float* dp_ = dW + (((size_t)s * 64 + k) * 16 + nb0) * 512 + col;
            dw0 = dp_[0]; dw1 = dp_[512]; dw2 = dp_[1024]; dw3 = dp_[1536];
        }

        // ===== layer 1: tail of pipeline chains into W2 block 0 =====
        float r0 = 0.f, r1 = 0.f, r2 = 0.f, r3 = 0.f;
        PIPE_LAYER(yq, W1, W2);
        acth[(cp * 4 + 0) * 2 + par] = f2h(tanhf(r0 + b1));
        acth[(cp * 4 + 1) * 2 + par] = f2h(tanhf(r1 + b1));
        acth[(cp * 4 + 2) * 2 + par] = f2h(tanhf(r2 + b1));
        acth[(cp * 4 + 3) * 2 + par] = f2h(tanhf(r3 + b1));
        __syncthreads();    // hs2/gs2 visible

        // ===== layer 2: tail chains into next step's W1 block 0 =====
        r0 = 0.f; r1 = 0.f; r2 = 0.f; r3 = 0.f;
        PIPE_LAYER(hq, W2, W1);
        if (net) {  // diffusion: 0.1*sigmoid(. + bg2) -> tmp2[r][col]
            tmp2[0][col] = 0.1f / (1.f + expf(-(r0 + b2)));
            tmp2[1][col] = 0.1f / (1.f + expf(-(r1 + b2)));
            tmp2[2][col] = 0.1f / (1.f + expf(-(r2 + b2)));
            tmp2[3][col] = 0.1f / (1.f + expf(-(r3 + b2)));
        }
        __syncthreads();    // tmp2 visible
        if (!net) { // drift finalizes: y += drift*dt + diff*(sqdt*dw)
            y0 += (r0 + b2) * DT_F + tmp2[0][col] * (SQDT_F * dw0);
            y1 += (r1 + b2) * DT_F + tmp2[1][col] * (SQDT_F * dw1);
            y2 += (r2 + b2) * DT_F + tmp2[2][col] * (SQDT_F * dw2);
            y3 += (r3 + b2) * DT_F + tmp2[3][col] * (SQDT_F * dw3);
            ysh[(cp * 4 + 0) * 2 + par] = f2h(y0);
            ysh[(cp * 4 + 1) * 2 + par] = f2h(y1);
            ysh[(cp * 4 + 2) * 2 + par] = f2h(y2);
            ysh[(cp * 4 + 3) * 2 + par] = f2h(y3);
            if ((s & 3) == 3) {
                const int t = s >> 2;
                float* pb = path + (((size_t)t * 64 + k) * 16 + nb0) * 512 + col;
                pb[0] = y0; pb[512] = y1; pb[1024] = y2; pb[1536] = y3;
            }
        }
        __syncthreads();    // ys2 ready for next step
    }
}

// ---------------------------------------------------------------------------
// SDE kernel (fp32 fallback = v9, bit-exact): used if workspace is too small.
// ---------------------------------------------------------------------------
__global__ __launch_bounds__(512, 1) void sde_f32_kernel(
    const float* __restrict__ init_mu, const float* __restrict__ init_noise,
    const float* __restrict__ Wf1, const float* __restrict__ bf1,
    const float* __restrict__ Wf2, const float* __restrict__ bf2,
    const float* __restrict__ Wg1, const float* __restrict__ bg1,
    const float* __restrict__ Wg2, const float* __restrict__ bg2,
    const float* __restrict__ dW, float* __restrict__ path)
{
    const int b    = blockIdx.x;
    const int xcd  = b & 7;
    const int slot = b >> 3;
    const int k    = xcd * 8 + (slot >> 2);
    const int q    = slot & 3;
    const int nb0  = q * 4;

    const int tid  = threadIdx.x;
    const int net  = tid >> 8;
    const int tt   = tid & 255;
    const int w    = tt >> 6;
    const int lane = tid & 63;
    const int wcol0 = w * 128;
    const int col  = wcol0 + 2 * lane;

    __shared__ __align__(16) float y_s[512][4];
    __shared__ __align__(16) float h_s[512][4];
    __shared__ __align__(16) float g_s[512][4];
    __shared__ __align__(16) float tmp[512][4];

    for (int idx = tid; idx < 2048; idx += 512) {
        int d = idx >> 2, r = idx & 3;
        y_s[d][r] = init_mu[k * 512 + d]
                  + 0.05f * init_noise[((size_t)(k * 16 + nb0 + r)) * 512 + d];
    }

    const size_t koff = (size_t)k * 262144;
    const float2* W1c = (const float2*)(((net ? Wg1 : Wf1) + koff) + col);
    const float2* W2c = (const float2*)(((net ? Wg2 : Wf2) + koff) + col);
    const float2 b1 = *(const float2*)((net ? bg1 : bf1) + k * 512 + col);
    const float2 b2 = *(const float2*)((net ? bg2 : bf2) + k * 512 + col);

    __syncthreads();

    for (int s = 0; s < NSTEP; ++s) {
        float2 dv0, dv1, dv2, dv3;
        if (!net) {
            const float* dp = dW + (((size_t)s * 64 + k) * 16 + nb0) * 512 + col;
            dv0 = *(const float2*)dp;
            dv1 = *(const float2*)(dp + 512);
            dv2 = *(const float2*)(dp + 1024);
            dv3 = *(const float2*)(dp + 1536);
        }

        float a00 = 0.f, a01 = 0.f, a10 = 0.f, a11 = 0.f;
        float a20 = 0.f, a21 = 0.f, a30 = 0.f, a31 = 0.f;
        #pragma unroll 16
        for (int d = 0; d < 512; ++d) {
            float2 wv = W1c[d * 256];
            float4 yv = *(const float4*)&y_s[d][0];
            a00 += yv.x * wv.x; a01 += yv.x * wv.y;
            a10 += yv.y * wv.x; a11 += yv.y * wv.y;
            a20 += yv.z * wv.x; a21 += yv.z * wv.y;
            a30 += yv.w * wv.x; a31 += yv.w * wv.y;
        }
        {
            float4 hv0 = make_float4(tanhf(a00 + b1.x), tanhf(a10 + b1.x),
                                     tanhf(a20 + b1.x), tanhf(a30 + b1.x));
            float4 hv1 = make_float4(tanhf(a01 + b1.y), tanhf(a11 + b1.y),
                                     tanhf(a21 + b1.y), tanhf(a31 + b1.y));
            float* hd = net ? &g_s[0][0] : &h_s[0][0];
            *(float4*)(hd + col * 4)       = hv0;
            *(float4*)(hd + (col + 1) * 4) = hv1;
        }
        __syncthreads();

        const float* hsp = net ? &g_s[0][0] : &h_s[0][0];
        float c00 = 0.f, c01 = 0.f, c10 = 0.f, c11 = 0.f;
        float c20 = 0.f, c21 = 0.f, c30 = 0.f, c31 = 0.f;
        #pragma unroll 16
        for (int hh = 0; hh < 512; ++hh) {
            float2 wv = W2c[hh * 256];
            float4 hv = *(const float4*)(hsp + hh * 4);
            c00 += hv.x * wv.x; c01 += hv.x * wv.y;
            c10 += hv.y * wv.x; c11 += hv.y * wv.y;
            c20 += hv.z * wv.x; c21 += hv.z * wv.y;
            c30 += hv.w * wv.x; c31 += hv.w * wv.y;
        }

        if (net) {
            float4 t0 = make_float4(0.1f / (1.f + expf(-(c00 + b2.x))),
                                    0.1f / (1.f + expf(-(c10 + b2.x))),
                                    0.1f / (1.f + expf(-(c20 + b2.x))),
                                    0.1f / (1.f + expf(-(c30 + b2.x))));
            float4 t1 = make_float4(0.1f / (1.f + expf(-(c01 + b2.y))),
                                    0.1f / (1.f + expf(-(c11 + b2.y))),
                                    0.1f / (1.f + expf(-(c21 + b2.y))),
                                    0.1f / (1.f + expf(-(c31 + b2.y))));
            *(float4*)&tmp[col][0]     = t0;
            *(float4*)&tmp[col + 1][0] = t1;
        }
        __syncthreads();
        if (!net) {
            float4 yo0 = *(const float4*)&y_s[col][0];
            float4 yo1 = *(const float4*)&y_s[col + 1][0];
            float4 tp0 = *(const float4*)&tmp[col][0];
            float4 tp1 = *(const float4*)&tmp[col + 1][0];
            float o00 = yo0.x + (c00 + b2.x) * DT_F + tp0.x * (SQDT_F * dv0.x);
            float o01 = yo1.x + (c01 + b2.y) * DT_F + tp1.x * (SQDT_F * dv0.y);
            float o10 = yo0.y + (c10 + b2.x) * DT_F + tp0.y * (SQDT_F * dv1.x);
            float o11 = yo1.y + (c11 + b2.y) * DT_F + tp1.y * (SQDT_F * dv1.y);
            float o20 = yo0.z + (c20 + b2.x) * DT_F + tp0.z * (SQDT_F * dv2.x);
            float o21 = yo1.z + (c21 + b2.y) * DT_F + tp1.z * (SQDT_F * dv2.y);
            float o30 = yo0.w + (c30 + b2.x) * DT_F + tp0.w * (SQDT_F * dv3.x);
            float o31 = yo1.w + (c31 + b2.y) * DT_F + tp1.w * (SQDT_F * dv3.y);
            *(float4*)&y_s[col][0]     = make_float4(o00, o10, o20, o30);
            *(float4*)&y_s[col + 1][0] = make_float4(o01, o11, o21, o31);
            if ((s & 3) == 3) {
                const int t = s >> 2;
                const size_t pb = (((size_t)t * 64 + k) * 16 + nb0) * 512 + col;
                *(float2*)(path + pb)        = make_float2(o00, o01);
                *(float2*)(path + pb + 512)  = make_float2(o10, o11);
                *(float2*)(path + pb + 1024) = make_float2(o20, o21);
                *(float2*)(path + pb + 1536) = make_float2(o30, o31);
            }
        }
        __syncthreads();
    }
}

// ---------------------------------------------------------------------------
// z row norms: znorm[t*512+j] = sum_d z[t][j][d]^2. One wave per row.
// ---------------------------------------------------------------------------
__global__ __launch_bounds__(256) void znorm_kernel(const float* __restrict__ z,
                                                    float* __restrict__ znorm)
{
    const int row  = blockIdx.x * 4 + (threadIdx.x >> 6);   // 0..4095
    const int lane = threadIdx.x & 63;
    const float* zr = z + (size_t)row * 512;
    float s = 0.f;
    for (int d = lane; d < 512; d += 64) { float v = zr[d]; s += v * v; }
    #pragma unroll
    for (int off = 32; off > 0; off >>= 1) s += __shfl_down(s, off);
    if (lane == 0) znorm[row] = s;
}

// ---------------------------------------------------------------------------
// G[t][i][j] = sum_d zhat[t][i][d] * z[t][j][d]   (A@B^T, both k-contiguous)
// tile 64x64, BK=64, 256 threads, 4x4 per thread.
// ---------------------------------------------------------------------------
__global__ __launch_bounds__(256) void gemm_kernel(const float* __restrict__ path,
                                                   const float* __restrict__ z,
                                                   float* __restrict__ G)
{
    const int jt = blockIdx.x;   // 0..7
    const int it = blockIdx.y;   // 0..15
    const int t  = blockIdx.z;   // 0..7
    const float* A  = path + (size_t)t * 1024 * 512 + (size_t)it * 64 * 512;
    const float* Bz = z    + (size_t)t * 512 * 512 + (size_t)jt * 64 * 512;
    float* Gp = G + (size_t)t * 1024 * 512 + (size_t)it * 64 * 512 + jt * 64;

    __shared__ float As[64][65];
    __shared__ float Bs[64][65];
    const int tid = threadIdx.x;
    const int tx = tid & 15, ty = tid >> 4;
    const int lr = tid >> 2;
    const int lc = (tid & 3) * 16;

    float acc[4][4] = {};
    for (int kt = 0; kt < 512; kt += 64) {
        #pragma unroll
        for (int u = 0; u < 4; ++u) {
            float4 av = *(const float4*)(A  + (size_t)lr * 512 + kt + lc + u * 4);
            float4 bv = *(const float4*)(Bz + (size_t)lr * 512 + kt + lc + u * 4);
            As[lr][lc + u * 4 + 0] = av.x; As[lr][lc + u * 4 + 1] = av.y;
            As[lr][lc + u * 4 + 2] = av.z; As[lr][lc + u * 4 + 3] = av.w;
            Bs[lr][lc + u * 4 + 0] = bv.x; Bs[lr][lc + u * 4 + 1] = bv.y;
            Bs[lr][lc + u * 4 + 2] = bv.z; Bs[lr][lc + u * 4 + 3] = bv.w;
        }
        __syncthreads();
        #pragma unroll 8
        for (int kk = 0; kk < 64; ++kk) {
            float a0 = As[ty][kk], a1 = As[ty + 16][kk], a2 = As[ty + 32][kk], a3 = As[ty + 48][kk];
            float b0 = Bs[tx][kk], b1 = Bs[tx + 16][kk], b2 = Bs[tx + 32][kk], b3 = Bs[tx + 48][kk];
            acc[0][0] += a0 * b0; acc[0][1] += a0 * b1; acc[0][2] += a0 * b2; acc[0][3] += a0 * b3;
            acc[1][0] += a1 * b0; acc[1][1] += a1 * b1; acc[1][2] += a1 * b2; acc[1][3] += a1 * b3;
            acc[2][0] += a2 * b0; acc[2][1] += a2 * b1; acc[2][2] += a2 * b2; acc[2][3] += a2 * b3;
            acc[3][0] += a3 * b0; acc[3][1] += a3 * b1; acc[3][2] += a3 * b2; acc[3][3] += a3 * b3;
        }
        __syncthreads();
    }
    #pragma unroll
    for (int mi = 0; mi < 4; ++mi)
        #pragma unroll
        for (int mj = 0; mj < 4; ++mj)
            Gp[(size_t)(ty + mi * 16) * 512 + tx + mj * 16] = acc[mi][mj];
}

// ---------------------------------------------------------------------------
// Per (t,i): argmax_j [2G - ||z_j||^2 + (y_j==cls ? 0 : -1e6)], then
// mse partial = sum_d (zhat[i,d] - z[pair,d])^2.  One block per (t,i).
// ---------------------------------------------------------------------------
__global__ __launch_bounds__(256) void pair_mse_kernel(
    const float* __restrict__ G, const float* __restrict__ znorm,
    const int* __restrict__ all_y, const float* __restrict__ path,
    const float* __restrict__ all_z, float* __restrict__ mse_part)
{
    const int t = blockIdx.x >> 10;
    const int i = blockIdx.x & 1023;
    const int cls = i >> 4;              // path_y[i] = i / NB
    const int tid = threadIdx.x;
    const float* Gr = G + ((size_t)t * 1024 + i) * 512;

    float best = -3.4e38f;
    int bestj = 0x7fffffff;
    for (int j = tid; j < 512; j += 256) {
        float sc = 2.f * Gr[j] - znorm[t * 512 + j];
        if (all_y[t * 512 + j] != cls) sc -= 1e6f;
        if (sc > best || (sc == best && j < bestj)) { best = sc; bestj = j; }
    }
    #pragma unroll
    for (int off = 32; off > 0; off >>= 1) {
        float ob = __shfl_down(best, off);
        int   oj = __shfl_down(bestj, off);
        if (ob > best || (ob == best && oj < bestj)) { best = ob; bestj = oj; }
    }
    __shared__ float sb[4];
    __shared__ int   sj[4];
    if ((tid & 63) == 0) { sb[tid >> 6] = best; sj[tid >> 6] = bestj; }
    __syncthreads();
    if (tid == 0) {
        for (int w = 1; w < 4; ++w)
            if (sb[w] > sb[0] || (sb[w] == sb[0] && sj[w] < sj[0])) { sb[0] = sb[w]; sj[0] = sj[w]; }
    }
    __syncthreads();
    const int pair = sj[0];

    const float* zh = path  + ((size_t)t * 1024 + i) * 512;
    const float* zr = all_z + ((size_t)t * 512 + pair) * 512;
    float ssum = 0.f;
    for (int d = tid; d < 512; d += 256) {
        float df = zh[d] - zr[d];
        ssum += df * df;
    }
    #pragma unroll
    for (int off = 32; off > 0; off >>= 1) ssum += __shfl_down(ssum, off);
    __shared__ float sred[4];
    if ((tid & 63) == 0) sred[tid >> 6] = ssum;
    __syncthreads();
    if (tid == 0) mse_part[blockIdx.x] = sred[0] + sred[1] + sred[2] + sred[3];
}

// ---------------------------------------------------------------------------
// CE: per (t, j-tile of 64). allc_j = sum_i e, pos_j = sum_{i: i/16==y_j} e,
// e = (sim<10 ? exp(sim) : 1).  ce_val[t*512+j] = log(allc+eps)-log(pos+eps)
// ---------------------------------------------------------------------------
__global__ __launch_bounds__(256) void ce_kernel(const float* __restrict__ G,
                                                 const int* __restrict__ all_y,
                                                 float* __restrict__ ce_val)
{
    const int t  = blockIdx.x >> 3;
    const int j0 = (blockIdx.x & 7) * 64;
    const int tid = threadIdx.x;
    const int jj = tid & 63, ig = tid >> 6;
    const int j = j0 + jj;
    const int cls = all_y[t * 512 + j];
    const float* Gt = G + (size_t)t * 1024 * 512;

    float alc = 0.f, pos = 0.f;
    for (int i = ig; i < 1024; i += 4) {
        float s = Gt[(size_t)i * 512 + j];
        float e = (s < 10.f) ? expf(s) : 1.f;
        alc += e;
        if ((i >> 4) == cls) pos += e;
    }
    __shared__ float as_[4][64];
    __shared__ float ps_[4][64];
    as_[ig][jj] = alc; ps_[ig][jj] = pos;
    __syncthreads();
    if (tid < 64) {
        float a = as_[0][tid] + as_[1][tid] + as_[2][tid] + as_[3][tid];
        float p = ps_[0][tid] + ps_[1][tid] + ps_[2][tid] + ps_[3][tid];
        ce_val[t * 512 + j0 + tid] = logf(a + 1e-7f) - logf(p + 1e-7f);
    }
}

// ---------------------------------------------------------------------------
// Final deterministic reduction: loss = mean_t( ce_t + mse_t )
// ---------------------------------------------------------------------------
__global__ __launch_bounds__(256) void final_kernel(const float* __restrict__ mse_part,
                                                    const float* __restrict__ ce_val,
                                                    float* __restrict__ out)
{
    const int tid = threadIdx.x;
    float ms = 0.f, cs = 0.f;
    for (int i = tid; i < 8192; i += 256) ms += mse_part[i];
    for (int i = tid; i < 4096; i += 256) cs += ce_val[i];
    #pragma unroll
    for (int off = 32; off > 0; off >>= 1) {
        ms += __shfl_down(ms, off);
        cs += __shfl_down(cs, off);
    }
    __shared__ float mred[4], cred[4];
    if ((tid & 63) == 0) { mred[tid >> 6] = ms; cred[tid >> 6] = cs; }
    __syncthreads();
    if (tid == 0) {
        float M = mred[0] + mred[1] + mred[2] + mred[3];
        float C = cred[0] + cred[1] + cred[2] + cred[3];
        out[0] = C / (8.f * 512.f) + M / (8.f * 1024.f * 512.f);
    }
}

extern "C" void kernel_launch(void* const* d_in, const int* in_sizes, int n_in,
                              void* d_out, int out_size, void* d_ws, size_t ws_size,
                              hipStream_t stream) {
    const float* all_z      = (const float*)d_in[0];
    const int*   all_y      = (const int*)d_in[1];
    const float* init_mu    = (const float*)d_in[2];
    const float* Wf1        = (const float*)d_in[3];
    const float* bf1        = (const float*)d_in[4];
    const float* Wf2        = (const float*)d_in[5];
    const float* bf2        = (const float*)d_in[6];
    const float* Wg1        = (const float*)d_in[7];
    const float* bg1        = (const float*)d_in[8];
    const float* Wg2        = (const float*)d_in[9];
    const float* bg2        = (const float*)d_in[10];
    const float* init_noise = (const float*)d_in[11];
    const float* dW         = (const float*)d_in[12];
    float* out = (float*)d_out;

    float* ws       = (float*)d_ws;
    float* path     = ws;                             // 8*64*16*512 = 4194304 floats
    float* G        = ws + (size_t)4194304;           // 8*1024*512  = 4194304 floats
    float* znorm    = G  + (size_t)4194304;           // 4096
    float* mse_part = znorm + 4096;                   // 8192
    float* ce_val   = mse_part + 8192;                // 4096
    uint4* Wq       = (uint4*)(ce_val + 4096);        // 8388608 uint4 = 128MB

    const size_t need = (size_t)(4194304 + 4194304 + 4096 + 8192 + 4096) * 4
                      + (size_t)8388608 * 16;

    if (ws_size >= need) {
        cvt_kernel<<<8192, 256, 0, stream>>>(Wf1, Wf2, Wg1, Wg2, Wq);
        sde_f16_kernel<<<256, 1024, 0, stream>>>(init_mu, init_noise, Wq,
                                                 bf1, bf2, bg1, bg2, dW, path);
    } else {
        sde_f32_kernel<<<256, 512, 0, stream>>>(init_mu, init_noise,
                                                Wf1, bf1, Wf2, bf2,
                                                Wg1, bg1, Wg2, bg2, dW, path);
    }
    znorm_kernel<<<1024, 256, 0, stream>>>(all_z, znorm);
    gemm_kernel<<<dim3(8, 16, 8), 256, 0, stream>>>(path, all_z, G);
    pair_mse_kernel<<<8192, 256, 0, stream>>>(G, znorm, all_y, path, all_z, mse_part);
    ce_kernel<<<64, 256, 0, stream>>>(G, all_y, ce_val);
    final_kernel<<<1, 256, 0, stream>>>(mse_part, ce_val, out);
}

// Round 14
// 1611.388 us; speedup vs baseline: 1.4270x; 1.4270x over previous
//
#include <hip/hip_runtime.h>
#include <math.h>

// Problem constants
#define T_C 8
#define K_C 64
#define NB_C 16
#define D_C 512
#define H_C 512
#define B_C 512
#define NSTEP 32          // only first 32 EM steps feed the loss (ys[3:32:4])
constexpr float DT_F   = 1.0f / 64.0f;
constexpr float SQDT_F = 0.125f;

typedef unsigned short ushort_t;

// ---------------------------------------------------------------------------
// v15: v13 structure + FP8(e4m3, x16-scaled) weight streaming.
// v14 post-mortem: 8-deep register pipeline SPILLED (WRITE_SIZE 16MB->1.6GB,
// scratch traffic) -> reverted. v13 is stream-bound: 2MB/step/CU at ~24 B/cyc
// == the whole 34us step. Rate attacks exhausted (occupancy +30% only, deep
// MLP spills); bytes have paid exactly as predicted twice (bf16, f16).
// v15 halves bytes again: weights quantized to e4m3 with exact x16 scale
// (sigma*16=0.7 mid-range, no denormals; underflow -> signed zero). Decode is
// branch-free plain bit math (no builtins/perm): prepass byte order
// [d0,d2,d1,d3] per dword makes ((W&0x7f007f)<<7)+0x20002000 | signs yield
// dpair-aligned f16x2 words feeding the existing dot2 path; one exact 2^-4
// rescale per accumulator. 64MB weight set -> fully LLC-resident.
// Falls back to the bit-exact fp32 v9 kernel if workspace is too small.
// ---------------------------------------------------------------------------

__device__ __forceinline__ ushort_t f2h(float f) {
    _Float16 h = (_Float16)f;                 // v_cvt_f16_f32 (RNE)
    union { _Float16 h; ushort_t u; } v; v.h = h; return v.u;
}

typedef _Float16 half2v __attribute__((ext_vector_type(2)));

__device__ __forceinline__ float dot2f(unsigned a2, unsigned b2, float acc) {
    union { unsigned u; half2v h; } a, b;
    a.u = a2; b.u = b2;
#if __has_builtin(__builtin_amdgcn_fdot2)
    return __builtin_amdgcn_fdot2(a.h, b.h, acc, false);  // v_dot2_f32_f16
#else
    return acc + (float)a.h.x * (float)b.h.x + (float)a.h.y * (float)b.h.y;
#endif
}

// fp32 -> e4m3fn byte of (f * 16), RNE; zero/underflow -> signed zero.
__device__ __forceinline__ unsigned f2e4m3s(float f) {
    unsigned h = (unsigned)f2h(f * 16.f);
    unsigned sign = (h >> 8) & 0x80u;
    unsigned exp  = (h >> 10) & 0x1fu;
    unsigned mant = h & 0x3ffu;
    if (exp == 0) return sign;                  // f16 zero/denormal
    unsigned m3  = mant >> 7;
    unsigned rem = mant & 0x7fu;
    if (rem > 0x40u || (rem == 0x40u && (m3 & 1u))) ++m3;
    int e = (int)exp - 8;                       // e4m3 exp field
    if (m3 == 8u) { m3 = 0u; ++e; }
    if (e <= 0) return sign;                    // underflow -> signed zero
    if (e > 15) { e = 15; m3 = 7u; }            // clamp (unreachable here)
    return sign | ((unsigned)e << 3) | m3;
}

// Decode one dword of bytes [dA, dB, dA', dB'] (order [d0,d2,d1,d3]) into
// two f16x2 words: w0 = (d0,d1), w1 = (d2,d3). f16 = sign<<15 |
// (field+8)<<10 | m3<<7 == ((byte&0x7f)<<7)+0x2000 with sign OR'd in.
__device__ __forceinline__ void dec4(unsigned W, unsigned& w0, unsigned& w1) {
    unsigned t  = W >> 8;
    unsigned f0 = ((W & 0x007f007fu) << 7) + 0x20002000u;
    unsigned f1 = ((t & 0x007f007fu) << 7) + 0x20002000u;
    w0 = ((W << 8) & 0x80008000u) | f0;
    w1 = (W & 0x80008000u) | f1;
}

// Prepass: per (k, layer L, net, d-oct, col) write uint2 of 8 e4m3 bytes,
// dword.x bytes = [w(8o),w(8o+2),w(8o+1),w(8o+3)], dword.y = same +4.
// Layout: Wb[(((k*2+L)*2+net)*64 + o)*512 + col].
__global__ __launch_bounds__(256) void cvt_kernel(
    const float* __restrict__ Wf1, const float* __restrict__ Wf2,
    const float* __restrict__ Wg1, const float* __restrict__ Wg2,
    uint2* __restrict__ Wb)
{
    for (unsigned u = blockIdx.x * 256 + threadIdx.x; u < 8388608u;
         u += 8192u * 256u) {
        unsigned col = u & 511u, o = (u >> 9) & 63u;
        unsigned net = (u >> 15) & 1u, L = (u >> 16) & 1u, k = u >> 17;
        const float* M = net ? (L ? Wg2 : Wg1) : (L ? Wf2 : Wf1);
        const float* p = M + (size_t)k * 262144 + (size_t)(8 * o) * 512 + col;
        unsigned c0 = f2e4m3s(p[0]),    c1 = f2e4m3s(p[512]);
        unsigned c2 = f2e4m3s(p[1024]), c3 = f2e4m3s(p[1536]);
        unsigned c4 = f2e4m3s(p[2048]), c5 = f2e4m3s(p[2560]);
        unsigned c6 = f2e4m3s(p[3072]), c7 = f2e4m3s(p[3584]);
        uint2 o2;
        o2.x = c0 | (c2 << 8) | (c1 << 16) | (c3 << 24);
        o2.y = c4 | (c6 << 8) | (c5 << 16) | (c7 << 24);
        Wb[u] = o2;
    }
}

// ---------------------------------------------------------------------------
// SDE kernel (fp8 weights, net-split): 256 blocks (4/k, 4 nb-rows), 1024 thr.
// Thread (net = tid>>9, col = tid&511) owns column `col` of net `net`.
// ---------------------------------------------------------------------------
__global__ __launch_bounds__(1024, 4) void sde_fp8_kernel(
    const float* __restrict__ init_mu, const float* __restrict__ init_noise,
    const uint2* __restrict__ Wb,
    const float* __restrict__ bf1, const float* __restrict__ bf2,
    const float* __restrict__ bg1, const float* __restrict__ bg2,
    const float* __restrict__ dW, float* __restrict__ path)
{
    // Quartet-on-one-XCD swizzle: siblings share their XCD's L2 weight lines.
    const int b    = blockIdx.x;
    const int xcd  = b & 7;
    const int slot = b >> 3;              // 0..31
    const int k    = xcd * 8 + (slot >> 2);
    const int q    = slot & 3;            // row-group within k
    const int nb0  = q * 4;               // this block's 4 nb-rows

    const int tid = threadIdx.x;
    const int net = tid >> 9;             // 0 = drift(f), 1 = diffusion(g)
    const int col = tid & 511;            // this thread's output column
    const int cp  = col >> 1;             // d-pair index of this column
    const int par = col & 1;              // low/high half within the pair

    __shared__ __align__(16) unsigned ys2[256][4];  // [dpair][row] f16x2
    __shared__ __align__(16) unsigned hs2[256][4];  // drift tanh
    __shared__ __align__(16) unsigned gs2[256][4];  // diffusion tanh
    __shared__ float tmp2[4][512];                  // diffusion sigmoid g->f

    // fp32 y-state for this column x rows 0..3 lives in f-net threads.
    float y0 = 0.f, y1 = 0.f, y2 = 0.f, y3 = 0.f;
    ushort_t* ysh = (ushort_t*)&ys2[0][0];
    if (!net) {
        const float* mu = init_mu + k * 512;
        const float* nz = init_noise + (size_t)(k * 16 + nb0) * 512;
        y0 = mu[col] + 0.05f * nz[col];
        y1 = mu[col] + 0.05f * nz[512 + col];
        y2 = mu[col] + 0.05f * nz[1024 + col];
        y3 = mu[col] + 0.05f * nz[1536 + col];
        ysh[(cp * 4 + 0) * 2 + par] = f2h(y0);
        ysh[(cp * 4 + 1) * 2 + par] = f2h(y1);
        ysh[(cp * 4 + 2) * 2 + par] = f2h(y2);
        ysh[(cp * 4 + 3) * 2 + par] = f2h(y3);
    }

    // Per-net fp8 weight segments (64 uint2-rows of 512 cols per layer).
    const uint2* W1 = Wb + (((size_t)k * 2 + 0) * 2 + net) * 32768 + col;
    const uint2* W2 = Wb + (((size_t)k * 2 + 1) * 2 + net) * 32768 + col;
    const float b1 = (net ? bg1 : bf1)[k * 512 + col];
    const float b2 = (net ? bg2 : bf2)[k * 512 + col];

    ushort_t* acth = (ushort_t*)(net ? &gs2[0][0] : &hs2[0][0]);
    const uint4* yq = (const uint4*)&ys2[0][0];
    const uint4* hq = (const uint4*)(net ? &gs2[0][0] : &hs2[0][0]);

    __syncthreads();             // ys2 ready

    for (int s = 0; s < NSTEP; ++s) {
        // dW for this column's 4 rows (f net only) — lands under layer 1.
        float dw0, dw1, dw2, dw3;
        if (!net) {
            const float* dp_ = dW + (((size_t)s * 64 + k) * 16 + nb0) * 512 + col;
            dw0 = dp_[0]; dw1 = dp_[512]; dw2 = dp_[1024]; dw3 = dp_[1536];
        }

        // ===== layer 1: a[r] = sum_d y[r][d] * W1[net][d][col] =====
        float a0 = 0.f, a1 = 0.f, a2 = 0.f, a3 = 0.f;
        #pragma unroll 8
        for (int o = 0; o < 64; ++o) {
            uint2 wb = W1[o * 512];            // 8B global: 8 fp8 weights
            unsigned w0, w1, w2, w3;
            dec4(wb.x, w0, w1);                // dpairs 4o+0, 4o+1
            dec4(wb.y, w2, w3);                // dpairs 4o+2, 4o+3
            uint4 ya = yq[4 * o + 0];
            uint4 yb = yq[4 * o + 1];
            uint4 yc = yq[4 * o + 2];
            uint4 yd = yq[4 * o + 3];
            a0 = dot2f(ya.x, w0, a0); a1 = dot2f(ya.y, w0, a1);
            a2 = dot2f(ya.z, w0, a2); a3 = dot2f(ya.w, w0, a3);
            a0 = dot2f(yb.x, w1, a0); a1 = dot2f(yb.y, w1, a1);
            a2 = dot2f(yb.z, w1, a2); a3 = dot2f(yb.w, w1, a3);
            a0 = dot2f(yc.x, w2, a0); a1 = dot2f(yc.y, w2, a1);
            a2 = dot2f(yc.z, w2, a2); a3 = dot2f(yc.w, w2, a3);
            a0 = dot2f(yd.x, w3, a0); a1 = dot2f(yd.y, w3, a1);
            a2 = dot2f(yd.z, w3, a2); a3 = dot2f(yd.w, w3, a3);
        }
        a0 *= 0.0625f; a1 *= 0.0625f; a2 *= 0.0625f; a3 *= 0.0625f;
        acth[(cp * 4 + 0) * 2 + par] = f2h(tanhf(a0 + b1));
        acth[(cp * 4 + 1) * 2 + par] = f2h(tanhf(a1 + b1));
        acth[(cp * 4 + 2) * 2 + par] = f2h(tanhf(a2 + b1));
        acth[(cp * 4 + 3) * 2 + par] = f2h(tanhf(a3 + b1));
        __syncthreads();    // hs2/gs2 visible

        // ===== layer 2: c[r] = sum_h act[r][h] * W2[net][h][col] =====
        float c0 = 0.f, c1 = 0.f, c2 = 0.f, c3 = 0.f;
        #pragma unroll 8
        for (int o = 0; o < 64; ++o) {
            uint2 wb = W2[o * 512];
            unsigned w0, w1, w2, w3;
            dec4(wb.x, w0, w1);
            dec4(wb.y, w2, w3);
            uint4 ha = hq[4 * o + 0];
            uint4 hb = hq[4 * o + 1];
            uint4 hc = hq[4 * o + 2];
            uint4 hd = hq[4 * o + 3];
            c0 = dot2f(ha.x, w0, c0); c1 = dot2f(ha.y, w0, c1);
            c2 = dot2f(ha.z, w0, c2); c3 = dot2f(ha.w, w0, c3);
            c0 = dot2f(hb.x, w1, c0); c1 = dot2f(hb.y, w1, c1);
            c2 = dot2f(hb.z, w1, c2); c3 = dot2f(hb.w, w1, c3);
            c0 = dot2f(hc.x, w2, c0); c1 = dot2f(hc.y, w2, c1);
            c2 = dot2f(hc.z, w2, c2); c3 = dot2f(hc.w, w2, c3);
            c0 = dot2f(hd.x, w3, c0); c1 = dot2f(hd.y, w3, c1);
            c2 = dot2f(hd.z, w3, c2); c3 = dot2f(hd.w, w3, c3);
        }
        c0 *= 0.0625f; c1 *= 0.0625f; c2 *= 0.0625f; c3 *= 0.0625f;

        if (net) {  // diffusion: 0.1*sigmoid(. + bg2) -> tmp2[r][col]
            tmp2[0][col] = 0.1f / (1.f + expf(-(c0 + b2)));
            tmp2[1][col] = 0.1f / (1.f + expf(-(c1 + b2)));
            tmp2[2][col] = 0.1f / (1.f + expf(-(c2 + b2)));
            tmp2[3][col] = 0.1f / (1.f + expf(-(c3 + b2)));
        }
        __syncthreads();    // tmp2 visible
        if (!net) { // drift finalizes: y += drift*dt + diff*(sqdt*dw)
            y0 += (c0 + b2) * DT_F + tmp2[0][col] * (SQDT_F * dw0);
            y1 += (c1 + b2) * DT_F + tmp2[1][col] * (SQDT_F * dw1);
            y2 += (c2 + b2) * DT_F + tmp2[2][col] * (SQDT_F * dw2);
            y3 += (c3 + b2) * DT_F + tmp2[3][col] * (SQDT_F * dw3);
            ysh[(cp * 4 + 0) * 2 + par] = f2h(y0);
            ysh[(cp * 4 + 1) * 2 + par] = f2h(y1);
            ysh[(cp * 4 + 2) * 2 + par] = f2h(y2);
            ysh[(cp * 4 + 3) * 2 + par] = f2h(y3);
            if ((s & 3) == 3) {
                const int t = s >> 2;
                float* pb = path + (((size_t)t * 64 + k) * 16 + nb0) * 512 + col;
                pb[0] = y0; pb[512] = y1; pb[1024] = y2; pb[1536] = y3;
            }
        }
        __syncthreads();    // ys2 ready for next step
    }
}

// ---------------------------------------------------------------------------
// SDE kernel (fp32 fallback = v9, bit-exact): used if workspace is too small.
// ---------------------------------------------------------------------------
__global__ __launch_bounds__(512, 1) void sde_f32_kernel(
    const float* __restrict__ init_mu, const float* __restrict__ init_noise,
    const float* __restrict__ Wf1, const float* __restrict__ bf1,
    const float* __restrict__ Wf2, const float* __restrict__ bf2,
    const float* __restrict__ Wg1, const float* __restrict__ bg1,
    const float* __restrict__ Wg2, const float* __restrict__ bg2,
    const float* __restrict__ dW, float* __restrict__ path)
{
    const int b    = blockIdx.x;
    const int xcd  = b & 7;
    const int slot = b >> 3;
    const int k    = xcd * 8 + (slot >> 2);
    const int q    = slot & 3;
    const int nb0  = q * 4;

    const int tid  = threadIdx.x;
    const int net  = tid >> 8;
    const int tt   = tid & 255;
    const int w    = tt >> 6;
    const int lane = tid & 63;
    const int wcol0 = w * 128;
    const int col  = wcol0 + 2 * lane;

    __shared__ __align__(16) float y_s[512][4];
    __shared__ __align__(16) float h_s[512][4];
    __shared__ __align__(16) float g_s[512][4];
    __shared__ __align__(16) float tmp[512][4];

    for (int idx = tid; idx < 2048; idx += 512) {
        int d = idx >> 2, r = idx & 3;
        y_s[d][r] = init_mu[k * 512 + d]
                  + 0.05f * init_noise[((size_t)(k * 16 + nb0 + r)) * 512 + d];
    }

    const size_t koff = (size_t)k * 262144;
    const float2* W1c = (const float2*)(((net ? Wg1 : Wf1) + koff) + col);
    const float2* W2c = (const float2*)(((net ? Wg2 : Wf2) + koff) + col);
    const float2 b1 = *(const float2*)((net ? bg1 : bf1) + k * 512 + col);
    const float2 b2 = *(const float2*)((net ? bg2 : bf2) + k * 512 + col);

    __syncthreads();

    for (int s = 0; s < NSTEP; ++s) {
        float2 dv0, dv1, dv2, dv3;
        if (!net) {
            const float* dp = dW + (((size_t)s * 64 + k) * 16 + nb0) * 512 + col;
            dv0 = *(const float2*)dp;
            dv1 = *(const float2*)(dp + 512);
            dv2 = *(const float2*)(dp + 1024);
            dv3 = *(const float2*)(dp + 1536);
        }

        float a00 = 0.f, a01 = 0.f, a10 = 0.f, a11 = 0.f;
        float a20 = 0.f, a21 = 0.f, a30 = 0.f, a31 = 0.f;
        #pragma unroll 16
        for (int d = 0; d < 512; ++d) {
            float2 wv = W1c[d * 256];
            float4 yv = *(const float4*)&y_s[d][0];
            a00 += yv.x * wv.x; a01 += yv.x * wv.y;
            a10 += yv.y * wv.x; a11 += yv.y * wv.y;
            a20 += yv.z * wv.x; a21 += yv.z * wv.y;
            a30 += yv.w * wv.x; a31 += yv.w * wv.y;
        }
        {
            float4 hv0 = make_float4(tanhf(a00 + b1.x), tanhf(a10 + b1.x),
                                     tanhf(a20 + b1.x), tanhf(a30 + b1.x));
            float4 hv1 = make_float4(tanhf(a01 + b1.y), tanhf(a11 + b1.y),
                                     tanhf(a21 + b1.y), tanhf(a31 + b1.y));
            float* hd = net ? &g_s[0][0] : &h_s[0][0];
            *(float4*)(hd + col * 4)       = hv0;
            *(float4*)(hd + (col + 1) * 4) = hv1;
        }
        __syncthreads();

        const float* hsp = net ? &g_s[0][0] : &h_s[0][0];
        float c00 = 0.f, c01 = 0.f, c10 = 0.f, c11 = 0.f;
        float c20 = 0.f, c21 = 0.f, c30 = 0.f, c31 = 0.f;
        #pragma unroll 16
        for (int hh = 0; hh < 512; ++hh) {
            float2 wv = W2c[hh * 256];
            float4 hv = *(const float4*)(hsp + hh * 4);
            c00 += hv.x * wv.x; c01 += hv.x * wv.y;
            c10 += hv.y * wv.x; c11 += hv.y * wv.y;
            c20 += hv.z * wv.x; c21 += hv.z * wv.y;
            c30 += hv.w * wv.x; c31 += hv.w * wv.y;
        }

        if (net) {
            float4 t0 = make_float4(0.1f / (1.f + expf(-(c00 + b2.x))),
                                    0.1f / (1.f + expf(-(c10 + b2.x))),
                                    0.1f / (1.f + expf(-(c20 + b2.x))),
                                    0.1f / (1.f + expf(-(c30 + b2.x))));
            float4 t1 = make_float4(0.1f / (1.f + expf(-(c01 + b2.y))),
                                    0.1f / (1.f + expf(-(c11 + b2.y))),
                                    0.1f / (1.f + expf(-(c21 + b2.y))),
                                    0.1f / (1.f + expf(-(c31 + b2.y))));
            *(float4*)&tmp[col][0]     = t0;
            *(float4*)&tmp[col + 1][0] = t1;
        }
        __syncthreads();
        if (!net) {
            float4 yo0 = *(const float4*)&y_s[col][0];
            float4 yo1 = *(const float4*)&y_s[col + 1][0];
            float4 tp0 = *(const float4*)&tmp[col][0];
            float4 tp1 = *(const float4*)&tmp[col + 1][0];
            float o00 = yo0.x + (c00 + b2.x) * DT_F + tp0.x * (SQDT_F * dv0.x);
            float o01 = yo1.x + (c01 + b2.y) * DT_F + tp1.x * (SQDT_F * dv0.y);
            float o10 = yo0.y + (c10 + b2.x) * DT_F + tp0.y * (SQDT_F * dv1.x);
            float o11 = yo1.y + (c11 + b2.y) * DT_F + tp1.y * (SQDT_F * dv1.y);
            float o20 = yo0.z + (c20 + b2.x) * DT_F + tp0.z * (SQDT_F * dv2.x);
            float o21 = yo1.z + (c21 + b2.y) * DT_F + tp1.z * (SQDT_F * dv2.y);
            float o30 = yo0.w + (c30 + b2.x) * DT_F + tp0.w * (SQDT_F * dv3.x);
            float o31 = yo1.w + (c31 + b2.y) * DT_F + tp1.w * (SQDT_F * dv3.y);
            *(float4*)&y_s[col][0]     = make_float4(o00, o10, o20, o30);
            *(float4*)&y_s[col + 1][0] = make_float4(o01, o11, o21, o31);
            if ((s & 3) == 3) {
                const int t = s >> 2;
                const size_t pb = (((size_t)t * 64 + k) * 16 + nb0) * 512 + col;
                *(float2*)(path + pb)        = make_float2(o00, o01);
                *(float2*)(path + pb + 512)  = make_float2(o10, o11);
                *(float2*)(path + pb + 1024) = make_float2(o20, o21);
                *(float2*)(path + pb + 1536) = make_float2(o30, o31);
            }
        }
        __syncthreads();
    }
}

// ---------------------------------------------------------------------------
// z row norms: znorm[t*512+j] = sum_d z[t][j][d]^2. One wave per row.
// ---------------------------------------------------------------------------
__global__ __launch_bounds__(256) void znorm_kernel(const float* __restrict__ z,
                                                    float* __restrict__ znorm)
{
    const int row  = blockIdx.x * 4 + (threadIdx.x >> 6);   // 0..4095
    const int lane = threadIdx.x & 63;
    const float* zr = z + (size_t)row * 512;
    float s = 0.f;
    for (int d = lane; d < 512; d += 64) { float v = zr[d]; s += v * v; }
    #pragma unroll
    for (int off = 32; off > 0; off >>= 1) s += __shfl_down(s, off);
    if (lane == 0) znorm[row] = s;
}

// ---------------------------------------------------------------------------
// G[t][i][j] = sum_d zhat[t][i][d] * z[t][j][d]   (A@B^T, both k-contiguous)
// tile 64x64, BK=64, 256 threads, 4x4 per thread.
// ---------------------------------------------------------------------------
__global__ __launch_bounds__(256) void gemm_kernel(const float* __restrict__ path,
                                                   const float* __restrict__ z,
                                                   float* __restrict__ G)
{
    const int jt = blockIdx.x;   // 0..7
    const int it = blockIdx.y;   // 0..15
    const int t  = blockIdx.z;   // 0..7
    const float* A  = path + (size_t)t * 1024 * 512 + (size_t)it * 64 * 512;
    const float* Bz = z    + (size_t)t * 512 * 512 + (size_t)jt * 64 * 512;
    float* Gp = G + (size_t)t * 1024 * 512 + (size_t)it * 64 * 512 + jt * 64;

    __shared__ float As[64][65];
    __shared__ float Bs[64][65];
    const int tid = threadIdx.x;
    const int tx = tid & 15, ty = tid >> 4;
    const int lr = tid >> 2;
    const int lc = (tid & 3) * 16;

    float acc[4][4] = {};
    for (int kt = 0; kt < 512; kt += 64) {
        #pragma unroll
        for (int u = 0; u < 4; ++u) {
            float4 av = *(const float4*)(A  + (size_t)lr * 512 + kt + lc + u * 4);
            float4 bv = *(const float4*)(Bz + (size_t)lr * 512 + kt + lc + u * 4);
            As[lr][lc + u * 4 + 0] = av.x; As[lr][lc + u * 4 + 1] = av.y;
            As[lr][lc + u * 4 + 2] = av.z; As[lr][lc + u * 4 + 3] = av.w;
            Bs[lr][lc + u * 4 + 0] = bv.x; Bs[lr][lc + u * 4 + 1] = bv.y;
            Bs[lr][lc + u * 4 + 2] = bv.z; Bs[lr][lc + u * 4 + 3] = bv.w;
        }
        __syncthreads();
        #pragma unroll 8
        for (int kk = 0; kk < 64; ++kk) {
            float a0 = As[ty][kk], a1 = As[ty + 16][kk], a2 = As[ty + 32][kk], a3 = As[ty + 48][kk];
            float b0 = Bs[tx][kk], b1 = Bs[tx + 16][kk], b2 = Bs[tx + 32][kk], b3 = Bs[tx + 48][kk];
            acc[0][0] += a0 * b0; acc[0][1] += a0 * b1; acc[0][2] += a0 * b2; acc[0][3] += a0 * b3;
            acc[1][0] += a1 * b0; acc[1][1] += a1 * b1; acc[1][2] += a1 * b2; acc[1][3] += a1 * b3;
            acc[2][0] += a2 * b0; acc[2][1] += a2 * b1; acc[2][2] += a2 * b2; acc[2][3] += a2 * b3;
            acc[3][0] += a3 * b0; acc[3][1] += a3 * b1; acc[3][2] += a3 * b2; acc[3][3] += a3 * b3;
        }
        __syncthreads();
    }
    #pragma unroll
    for (int mi = 0; mi < 4; ++mi)
        #pragma unroll
        for (int mj = 0; mj < 4; ++mj)
            Gp[(size_t)(ty + mi * 16) * 512 + tx + mj * 16] = acc[mi][mj];
}

// ---------------------------------------------------------------------------
// Per (t,i): argmax_j [2G - ||z_j||^2 + (y_j==cls ? 0 : -1e6)], then
// mse partial = sum_d (zhat[i,d] - z[pair,d])^2.  One block per (t,i).
// ---------------------------------------------------------------------------
__global__ __launch_bounds__(256) void pair_mse_kernel(
    const float* __restrict__ G, const float* __restrict__ znorm,
    const int* __restrict__ all_y, const float* __restrict__ path,
    const float* __restrict__ all_z, float* __restrict__ mse_part)
{
    const int t = blockIdx.x >> 10;
    const int i = blockIdx.x & 1023;
    const int cls = i >> 4;              // path_y[i] = i / NB
    const int tid = threadIdx.x;
    const float* Gr = G + ((size_t)t * 1024 + i) * 512;

    float best = -3.4e38f;
    int bestj = 0x7fffffff;
    for (int j = tid; j < 512; j += 256) {
        float sc = 2.f * Gr[j] - znorm[t * 512 + j];
        if (all_y[t * 512 + j] != cls) sc -= 1e6f;
        if (sc > best || (sc == best && j < bestj)) { best = sc; bestj = j; }
    }
    #pragma unroll
    for (int off = 32; off > 0; off >>= 1) {
        float ob = __shfl_down(best, off);
        int   oj = __shfl_down(bestj, off);
        if (ob > best || (ob == best && oj < bestj)) { best = ob; bestj = oj; }
    }
    __shared__ float sb[4];
    __shared__ int   sj[4];
    if ((tid & 63) == 0) { sb[tid >> 6] = best; sj[tid >> 6] = bestj; }
    __syncthreads();
    if (tid == 0) {
        for (int w = 1; w < 4; ++w)
            if (sb[w] > sb[0] || (sb[w] == sb[0] && sj[w] < sj[0])) { sb[0] = sb[w]; sj[0] = sj[w]; }
    }
    __syncthreads();
    const int pair = sj[0];

    const float* zh = path  + ((size_t)t * 1024 + i) * 512;
    const float* zr = all_z + ((size_t)t * 512 + pair) * 512;
    float ssum = 0.f;
    for (int d = tid; d < 512; d += 256) {
        float df = zh[d] - zr[d];
        ssum += df * df;
    }
    #pragma unroll
    for (int off = 32; off > 0; off >>= 1) ssum += __shfl_down(ssum, off);
    __shared__ float sred[4];
    if ((tid & 63) == 0) sred[tid >> 6] = ssum;
    __syncthreads();
    if (tid == 0) mse_part[blockIdx.x] = sred[0] + sred[1] + sred[2] + sred[3];
}

// ---------------------------------------------------------------------------
// CE: per (t, j-tile of 64). allc_j = sum_i e, pos_j = sum_{i: i/16==y_j} e,
// e = (sim<10 ? exp(sim) : 1).  ce_val[t*512+j] = log(allc+eps)-log(pos+eps)
// ---------------------------------------------------------------------------
__global__ __launch_bounds__(256) void ce_kernel(const float* __restrict__ G,
                                                 const int* __restrict__ all_y,
                                                 float* __restrict__ ce_val)
{
    const int t  = blockIdx.x >> 3;
    const int j0 = (blockIdx.x & 7) * 64;
    const int tid = threadIdx.x;
    const int jj = tid & 63, ig = tid >> 6;
    const int j = j0 + jj;
    const int cls = all_y[t * 512 + j];
    const float* Gt = G + (size_t)t * 1024 * 512;

    float alc = 0.f, pos = 0.f;
    for (int i = ig; i < 1024; i += 4) {
        float s = Gt[(size_t)i * 512 + j];
        float e = (s < 10.f) ? expf(s) : 1.f;
        alc += e;
        if ((i >> 4) == cls) pos += e;
    }
    __shared__ float as_[4][64];
    __shared__ float ps_[4][64];
    as_[ig][jj] = alc; ps_[ig][jj] = pos;
    __syncthreads();
    if (tid < 64) {
        float a = as_[0][tid] + as_[1][tid] + as_[2][tid] + as_[3][tid];
        float p = ps_[0][tid] + ps_[1][tid] + ps_[2][tid] + ps_[3][tid];
        ce_val[t * 512 + j0 + tid] = logf(a + 1e-7f) - logf(p + 1e-7f);
    }
}

// ---------------------------------------------------------------------------
// Final deterministic reduction: loss = mean_t( ce_t + mse_t )
// ---------------------------------------------------------------------------
__global__ __launch_bounds__(256) void final_kernel(const float* __restrict__ mse_part,
                                                    const float* __restrict__ ce_val,
                                                    float* __restrict__ out)
{
    const int tid = threadIdx.x;
    float ms = 0.f, cs = 0.f;
    for (int i = tid; i < 8192; i += 256) ms += mse_part[i];
    for (int i = tid; i < 4096; i += 256) cs += ce_val[i];
    #pragma unroll
    for (int off = 32; off > 0; off >>= 1) {
        ms += __shfl_down(ms, off);
        cs += __shfl_down(cs, off);
    }
    __shared__ float mred[4], cred[4];
    if ((tid & 63) == 0) { mred[tid >> 6] = ms; cred[tid >> 6] = cs; }
    __syncthreads();
    if (tid == 0) {
        float M = mred[0] + mred[1] + mred[2] + mred[3];
        float C = cred[0] + cred[1] + cred[2] + cred[3];
        out[0] = C / (8.f * 512.f) + M / (8.f * 1024.f * 512.f);
    }
}

extern "C" void kernel_launch(void* const* d_in, const int* in_sizes, int n_in,
                              void* d_out, int out_size, void* d_ws, size_t ws_size,
                              hipStream_t stream) {
    const float* all_z      = (const float*)d_in[0];
    const int*   all_y      = (const int*)d_in[1];
    const float* init_mu    = (const float*)d_in[2];
    const float* Wf1        = (const float*)d_in[3];
    const float* bf1        = (const float*)d_in[4];
    const float* Wf2        = (const float*)d_in[5];
    const float* bf2        = (const float*)d_in[6];
    const float* Wg1        = (const float*)d_in[7];
    const float* bg1        = (const float*)d_in[8];
    const float* Wg2        = (const float*)d_in[9];
    const float* bg2        = (const float*)d_in[10];
    const float* init_noise = (const float*)d_in[11];
    const float* dW         = (const float*)d_in[12];
    float* out = (float*)d_out;

    float* ws       = (float*)d_ws;
    float* path     = ws;                             // 8*64*16*512 = 4194304 floats
    float* G        = ws + (size_t)4194304;           // 8*1024*512  = 4194304 floats
    float* znorm    = G  + (size_t)4194304;           // 4096
    float* mse_part = znorm + 4096;                   // 8192
    float* ce_val   = mse_part + 8192;                // 4096
    uint2* Wb       = (uint2*)(ce_val + 4096);        // 8388608 uint2 = 64MB

    const size_t need = (size_t)(4194304 + 4194304 + 4096 + 8192 + 4096) * 4
                      + (size_t)8388608 * 8;

    if (ws_size >= need) {
        cvt_kernel<<<8192, 256, 0, stream>>>(Wf1, Wf2, Wg1, Wg2, Wb);
        sde_fp8_kernel<<<256, 1024, 0, stream>>>(init_mu, init_noise, Wb,
                                                 bf1, bf2, bg1, bg2, dW, path);
    } else {
        sde_f32_kernel<<<256, 512, 0, stream>>>(init_mu, init_noise,
                                                Wf1, bf1, Wf2, bf2,
                                                Wg1, bg1, Wg2, bg2, dW, path);
    }
    znorm_kernel<<<1024, 256, 0, stream>>>(all_z, znorm);
    gemm_kernel<<<dim3(8, 16, 8), 256, 0, stream>>>(path, all_z, G);
    pair_mse_kernel<<<8192, 256, 0, stream>>>(G, znorm, all_y, path, all_z, mse_part);
    ce_kernel<<<64, 256, 0, stream>>>(G, all_y, ce_val);
    final_kernel<<<1, 256, 0, stream>>>(mse_part, ce_val, out);
}

// Round 15
// 1273.197 us; speedup vs baseline: 1.8060x; 1.2656x over previous
//
#include <hip/hip_runtime.h>
#include <math.h>

// Problem constants
#define T_C 8
#define K_C 64
#define NB_C 16
#define D_C 512
#define H_C 512
#define B_C 512
#define NSTEP 32          // only first 32 EM steps feed the loss (ys[3:32:4])
constexpr float DT_F   = 1.0f / 64.0f;
constexpr float SQDT_F = 0.125f;

typedef unsigned short ushort_t;

// ---------------------------------------------------------------------------
// v16 == v13 (REVERT; best verified: 1276us total, sde 1100us, absmax 0.0).
// Trade-space fully mapped across rounds:
//   f32 stream 4MB/step/CU -> 72us step (stream-bound)
//   f16+dot2 2MB          -> 34.4us    (stream-bound)  <- THIS KERNEL
//   fp8+decode 1MB        -> 46us      (VALU-bound: decode ~34us/step)
//   8-deep reg pipeline   -> spills (WRITE_SIZE 16MB->1.6GB)
// Per-CU ingest ~24 B/cyc held across 5 staging schemes (DMA ring, LDS
// stage, plain loads, 2x occupancy, deep pipe) -> sustained HW ingest rate
// for this pattern. v13 step time == weight-stream time; VALU+LDS hidden.
// Net-split 1024-thread blocks: thread=(net,col) owns 1 column of 1 net,
// 4 rows; weights f16, 8 consecutive d per uint4 (16B/lane, coalesced);
// fp32 y-state in f-net registers (never quantized); fp32 accumulate,
// d-order sequential. XCD-quartet swizzle dedups sibling streams in L2.
// Falls back to the bit-exact fp32 v9 kernel if workspace is too small.
// ---------------------------------------------------------------------------

__device__ __forceinline__ ushort_t f2h(float f) {
    _Float16 h = (_Float16)f;                 // v_cvt_f16_f32 (RNE)
    union { _Float16 h; ushort_t u; } v; v.h = h; return v.u;
}

typedef _Float16 half2v __attribute__((ext_vector_type(2)));

__device__ __forceinline__ float dot2f(unsigned a2, unsigned b2, float acc) {
    union { unsigned u; half2v h; } a, b;
    a.u = a2; b.u = b2;
#if __has_builtin(__builtin_amdgcn_fdot2)
    return __builtin_amdgcn_fdot2(a.h, b.h, acc, false);  // v_dot2_f32_f16
#else
    return acc + (float)a.h.x * (float)b.h.x + (float)a.h.y * (float)b.h.y;
#endif
}

__device__ __forceinline__ unsigned pkh(float a, float b) {
    return (unsigned)f2h(a) | ((unsigned)f2h(b) << 16);
}

// Prepass: per (k, layer L, net, d-oct, col) write uint4 =
//   { pkh(w[8o][c],w[8o+1][c]), pkh(w[8o+2],w[8o+3]),
//     pkh(w[8o+4],w[8o+5]),    pkh(w[8o+6],w[8o+7]) }
// Segment layout: Wq[(((k*2+L)*2+net)*64 + o)*512 + col].
__global__ __launch_bounds__(256) void cvt_kernel(
    const float* __restrict__ Wf1, const float* __restrict__ Wf2,
    const float* __restrict__ Wg1, const float* __restrict__ Wg2,
    uint4* __restrict__ Wq)
{
    for (unsigned u = blockIdx.x * 256 + threadIdx.x; u < 8388608u;
         u += 8192u * 256u) {
        unsigned col = u & 511u, o = (u >> 9) & 63u;
        unsigned net = (u >> 15) & 1u, L = (u >> 16) & 1u, k = u >> 17;
        const float* M = net ? (L ? Wg2 : Wg1) : (L ? Wf2 : Wf1);
        size_t ib = (size_t)k * 262144 + (size_t)(8 * o) * 512 + col;
        uint4 w;
        w.x = pkh(M[ib],        M[ib + 512]);
        w.y = pkh(M[ib + 1024], M[ib + 1536]);
        w.z = pkh(M[ib + 2048], M[ib + 2560]);
        w.w = pkh(M[ib + 3072], M[ib + 3584]);
        Wq[u] = w;
    }
}

// ---------------------------------------------------------------------------
// SDE kernel (f16, net-split): 256 blocks (4 per k, 4 nb-rows), 1024 threads.
// Thread (net = tid>>9, col = tid&511) owns column `col` of net `net`.
// ---------------------------------------------------------------------------
__global__ __launch_bounds__(1024, 4) void sde_f16_kernel(
    const float* __restrict__ init_mu, const float* __restrict__ init_noise,
    const uint4* __restrict__ Wq,
    const float* __restrict__ bf1, const float* __restrict__ bf2,
    const float* __restrict__ bg1, const float* __restrict__ bg2,
    const float* __restrict__ dW, float* __restrict__ path)
{
    // Quartet-on-one-XCD swizzle: siblings share their XCD's L2 weight lines.
    const int b    = blockIdx.x;
    const int xcd  = b & 7;
    const int slot = b >> 3;              // 0..31
    const int k    = xcd * 8 + (slot >> 2);
    const int q    = slot & 3;            // row-group within k
    const int nb0  = q * 4;               // this block's 4 nb-rows

    const int tid = threadIdx.x;
    const int net = tid >> 9;             // 0 = drift(f), 1 = diffusion(g)
    const int col = tid & 511;            // this thread's output column
    const int cp  = col >> 1;             // d-pair index of this column
    const int par = col & 1;              // low/high half within the pair

    __shared__ __align__(16) unsigned ys2[256][4];  // [dpair][row] f16x2
    __shared__ __align__(16) unsigned hs2[256][4];  // drift tanh
    __shared__ __align__(16) unsigned gs2[256][4];  // diffusion tanh
    __shared__ float tmp2[4][512];                  // diffusion sigmoid g->f

    // fp32 y-state for this column x rows 0..3 lives in f-net threads.
    float y0 = 0.f, y1 = 0.f, y2 = 0.f, y3 = 0.f;
    ushort_t* ysh = (ushort_t*)&ys2[0][0];
    if (!net) {
        const float* mu = init_mu + k * 512;
        const float* nz = init_noise + (size_t)(k * 16 + nb0) * 512;
        y0 = mu[col] + 0.05f * nz[col];
        y1 = mu[col] + 0.05f * nz[512 + col];
        y2 = mu[col] + 0.05f * nz[1024 + col];
        y3 = mu[col] + 0.05f * nz[1536 + col];
        ysh[(cp * 4 + 0) * 2 + par] = f2h(y0);
        ysh[(cp * 4 + 1) * 2 + par] = f2h(y1);
        ysh[(cp * 4 + 2) * 2 + par] = f2h(y2);
        ysh[(cp * 4 + 3) * 2 + par] = f2h(y3);
    }

    // Per-net weight segments (64 uint4-rows of 512 cols per layer).
    const uint4* W1 = Wq + (((size_t)k * 2 + 0) * 2 + net) * 32768 + col;
    const uint4* W2 = Wq + (((size_t)k * 2 + 1) * 2 + net) * 32768 + col;
    const float b1 = (net ? bg1 : bf1)[k * 512 + col];
    const float b2 = (net ? bg2 : bf2)[k * 512 + col];

    ushort_t* acth = (ushort_t*)(net ? &gs2[0][0] : &hs2[0][0]);

    __syncthreads();             // ys2 ready

    for (int s = 0; s < NSTEP; ++s) {
        // dW for this column's 4 rows (f net only) — lands under layer 1.
        float dw0, dw1, dw2, dw3;
        if (!net) {
            const float* dp_ = dW + (((size_t)s * 64 + k) * 16 + nb0) * 512 + col;
            dw0 = dp_[0]; dw1 = dp_[512]; dw2 = dp_[1024]; dw3 = dp_[1536];
        }

        // ===== layer 1: a[r] = sum_d y[r][d] * W1[net][d][col] =====
        float a0 = 0.f, a1 = 0.f, a2 = 0.f, a3 = 0.f;
        const uint4* yq = (const uint4*)&ys2[0][0];
        #pragma unroll 8
        for (int o = 0; o < 64; ++o) {
            uint4 wv = W1[o * 512];            // 16B global, coalesced
            uint4 ya = yq[4 * o + 0];          // rows 0..3 @ dpair 4o+0
            uint4 yb = yq[4 * o + 1];
            uint4 yc = yq[4 * o + 2];
            uint4 yd = yq[4 * o + 3];
            a0 = dot2f(ya.x, wv.x, a0); a1 = dot2f(ya.y, wv.x, a1);
            a2 = dot2f(ya.z, wv.x, a2); a3 = dot2f(ya.w, wv.x, a3);
            a0 = dot2f(yb.x, wv.y, a0); a1 = dot2f(yb.y, wv.y, a1);
            a2 = dot2f(yb.z, wv.y, a2); a3 = dot2f(yb.w, wv.y, a3);
            a0 = dot2f(yc.x, wv.z, a0); a1 = dot2f(yc.y, wv.z, a1);
            a2 = dot2f(yc.z, wv.z, a2); a3 = dot2f(yc.w, wv.z, a3);
            a0 = dot2f(yd.x, wv.w, a0); a1 = dot2f(yd.y, wv.w, a1);
            a2 = dot2f(yd.z, wv.w, a2); a3 = dot2f(yd.w, wv.w, a3);
        }
        acth[(cp * 4 + 0) * 2 + par] = f2h(tanhf(a0 + b1));
        acth[(cp * 4 + 1) * 2 + par] = f2h(tanhf(a1 + b1));
        acth[(cp * 4 + 2) * 2 + par] = f2h(tanhf(a2 + b1));
        acth[(cp * 4 + 3) * 2 + par] = f2h(tanhf(a3 + b1));
        __syncthreads();    // hs2/gs2 visible

        // ===== layer 2: c[r] = sum_h act[r][h] * W2[net][h][col] =====
        float c0 = 0.f, c1 = 0.f, c2 = 0.f, c3 = 0.f;
        const uint4* hq = (const uint4*)(net ? &gs2[0][0] : &hs2[0][0]);
        #pragma unroll 8
        for (int o = 0; o < 64; ++o) {
            uint4 wv = W2[o * 512];
            uint4 ha = hq[4 * o + 0];
            uint4 hb = hq[4 * o + 1];
            uint4 hc = hq[4 * o + 2];
            uint4 hd = hq[4 * o + 3];
            c0 = dot2f(ha.x, wv.x, c0); c1 = dot2f(ha.y, wv.x, c1);
            c2 = dot2f(ha.z, wv.x, c2); c3 = dot2f(ha.w, wv.x, c3);
            c0 = dot2f(hb.x, wv.y, c0); c1 = dot2f(hb.y, wv.y, c1);
            c2 = dot2f(hb.z, wv.y, c2); c3 = dot2f(hb.w, wv.y, c3);
            c0 = dot2f(hc.x, wv.z, c0); c1 = dot2f(hc.y, wv.z, c1);
            c2 = dot2f(hc.z, wv.z, c2); c3 = dot2f(hc.w, wv.z, c3);
            c0 = dot2f(hd.x, wv.w, c0); c1 = dot2f(hd.y, wv.w, c1);
            c2 = dot2f(hd.z, wv.w, c2); c3 = dot2f(hd.w, wv.w, c3);
        }

        if (net) {  // diffusion: 0.1*sigmoid(. + bg2) -> tmp2[r][col]
            tmp2[0][col] = 0.1f / (1.f + expf(-(c0 + b2)));
            tmp2[1][col] = 0.1f / (1.f + expf(-(c1 + b2)));
            tmp2[2][col] = 0.1f / (1.f + expf(-(c2 + b2)));
            tmp2[3][col] = 0.1f / (1.f + expf(-(c3 + b2)));
        }
        __syncthreads();    // tmp2 visible
        if (!net) { // drift finalizes: y += drift*dt + diff*(sqdt*dw)
            y0 += (c0 + b2) * DT_F + tmp2[0][col] * (SQDT_F * dw0);
            y1 += (c1 + b2) * DT_F + tmp2[1][col] * (SQDT_F * dw1);
            y2 += (c2 + b2) * DT_F + tmp2[2][col] * (SQDT_F * dw2);
            y3 += (c3 + b2) * DT_F + tmp2[3][col] * (SQDT_F * dw3);
            ysh[(cp * 4 + 0) * 2 + par] = f2h(y0);
            ysh[(cp * 4 + 1) * 2 + par] = f2h(y1);
            ysh[(cp * 4 + 2) * 2 + par] = f2h(y2);
            ysh[(cp * 4 + 3) * 2 + par] = f2h(y3);
            if ((s & 3) == 3) {
                const int t = s >> 2;
                float* pb = path + (((size_t)t * 64 + k) * 16 + nb0) * 512 + col;
                pb[0] = y0; pb[512] = y1; pb[1024] = y2; pb[1536] = y3;
            }
        }
        __syncthreads();    // ys2 ready for next step
    }
}

// ---------------------------------------------------------------------------
// SDE kernel (fp32 fallback = v9, bit-exact): used if workspace is too small.
// ---------------------------------------------------------------------------
__global__ __launch_bounds__(512, 1) void sde_f32_kernel(
    const float* __restrict__ init_mu, const float* __restrict__ init_noise,
    const float* __restrict__ Wf1, const float* __restrict__ bf1,
    const float* __restrict__ Wf2, const float* __restrict__ bf2,
    const float* __restrict__ Wg1, const float* __restrict__ bg1,
    const float* __restrict__ Wg2, const float* __restrict__ bg2,
    const float* __restrict__ dW, float* __restrict__ path)
{
    const int b    = blockIdx.x;
    const int xcd  = b & 7;
    const int slot = b >> 3;
    const int k    = xcd * 8 + (slot >> 2);
    const int q    = slot & 3;
    const int nb0  = q * 4;

    const int tid  = threadIdx.x;
    const int net  = tid >> 8;
    const int tt   = tid & 255;
    const int w    = tt >> 6;
    const int lane = tid & 63;
    const int wcol0 = w * 128;
    const int col  = wcol0 + 2 * lane;

    __shared__ __align__(16) float y_s[512][4];
    __shared__ __align__(16) float h_s[512][4];
    __shared__ __align__(16) float g_s[512][4];
    __shared__ __align__(16) float tmp[512][4];

    for (int idx = tid; idx < 2048; idx += 512) {
        int d = idx >> 2, r = idx & 3;
        y_s[d][r] = init_mu[k * 512 + d]
                  + 0.05f * init_noise[((size_t)(k * 16 + nb0 + r)) * 512 + d];
    }

    const size_t koff = (size_t)k * 262144;
    const float2* W1c = (const float2*)(((net ? Wg1 : Wf1) + koff) + col);
    const float2* W2c = (const float2*)(((net ? Wg2 : Wf2) + koff) + col);
    const float2 b1 = *(const float2*)((net ? bg1 : bf1) + k * 512 + col);
    const float2 b2 = *(const float2*)((net ? bg2 : bf2) + k * 512 + col);

    __syncthreads();

    for (int s = 0; s < NSTEP; ++s) {
        float2 dv0, dv1, dv2, dv3;
        if (!net) {
            const float* dp = dW + (((size_t)s * 64 + k) * 16 + nb0) * 512 + col;
            dv0 = *(const float2*)dp;
            dv1 = *(const float2*)(dp + 512);
            dv2 = *(const float2*)(dp + 1024);
            dv3 = *(const float2*)(dp + 1536);
        }

        float a00 = 0.f, a01 = 0.f, a10 = 0.f, a11 = 0.f;
        float a20 = 0.f, a21 = 0.f, a30 = 0.f, a31 = 0.f;
        #pragma unroll 16
        for (int d = 0; d < 512; ++d) {
            float2 wv = W1c[d * 256];
            float4 yv = *(const float4*)&y_s[d][0];
            a00 += yv.x * wv.x; a01 += yv.x * wv.y;
            a10 += yv.y * wv.x; a11 += yv.y * wv.y;
            a20 += yv.z * wv.x; a21 += yv.z * wv.y;
            a30 += yv.w * wv.x; a31 += yv.w * wv.y;
        }
        {
            float4 hv0 = make_float4(tanhf(a00 + b1.x), tanhf(a10 + b1.x),
                                     tanhf(a20 + b1.x), tanhf(a30 + b1.x));
            float4 hv1 = make_float4(tanhf(a01 + b1.y), tanhf(a11 + b1.y),
                                     tanhf(a21 + b1.y), tanhf(a31 + b1.y));
            float* hd = net ? &g_s[0][0] : &h_s[0][0];
            *(float4*)(hd + col * 4)       = hv0;
            *(float4*)(hd + (col + 1) * 4) = hv1;
        }
        __syncthreads();

        const float* hsp = net ? &g_s[0][0] : &h_s[0][0];
        float c00 = 0.f, c01 = 0.f, c10 = 0.f, c11 = 0.f;
        float c20 = 0.f, c21 = 0.f, c30 = 0.f, c31 = 0.f;
        #pragma unroll 16
        for (int hh = 0; hh < 512; ++hh) {
            float2 wv = W2c[hh * 256];
            float4 hv = *(const float4*)(hsp + hh * 4);
            c00 += hv.x * wv.x; c01 += hv.x * wv.y;
            c10 += hv.y * wv.x; c11 += hv.y * wv.y;
            c20 += hv.z * wv.x; c21 += hv.z * wv.y;
            c30 += hv.w * wv.x; c31 += hv.w * wv.y;
        }

        if (net) {
            float4 t0 = make_float4(0.1f / (1.f + expf(-(c00 + b2.x))),
                                    0.1f / (1.f + expf(-(c10 + b2.x))),
                                    0.1f / (1.f + expf(-(c20 + b2.x))),
                                    0.1f / (1.f + expf(-(c30 + b2.x))));
            float4 t1 = make_float4(0.1f / (1.f + expf(-(c01 + b2.y))),
                                    0.1f / (1.f + expf(-(c11 + b2.y))),
                                    0.1f / (1.f + expf(-(c21 + b2.y))),
                                    0.1f / (1.f + expf(-(c31 + b2.y))));
            *(float4*)&tmp[col][0]     = t0;
            *(float4*)&tmp[col + 1][0] = t1;
        }
        __syncthreads();
        if (!net) {
            float4 yo0 = *(const float4*)&y_s[col][0];
            float4 yo1 = *(const float4*)&y_s[col + 1][0];
            float4 tp0 = *(const float4*)&tmp[col][0];
            float4 tp1 = *(const float4*)&tmp[col + 1][0];
            float o00 = yo0.x + (c00 + b2.x) * DT_F + tp0.x * (SQDT_F * dv0.x);
            float o01 = yo1.x + (c01 + b2.y) * DT_F + tp1.x * (SQDT_F * dv0.y);
            float o10 = yo0.y + (c10 + b2.x) * DT_F + tp0.y * (SQDT_F * dv1.x);
            float o11 = yo1.y + (c11 + b2.y) * DT_F + tp1.y * (SQDT_F * dv1.y);
            float o20 = yo0.z + (c20 + b2.x) * DT_F + tp0.z * (SQDT_F * dv2.x);
            float o21 = yo1.z + (c21 + b2.y) * DT_F + tp1.z * (SQDT_F * dv2.y);
            float o30 = yo0.w + (c30 + b2.x) * DT_F + tp0.w * (SQDT_F * dv3.x);
            float o31 = yo1.w + (c31 + b2.y) * DT_F + tp1.w * (SQDT_F * dv3.y);
            *(float4*)&y_s[col][0]     = make_float4(o00, o10, o20, o30);
            *(float4*)&y_s[col + 1][0] = make_float4(o01, o11, o21, o31);
            if ((s & 3) == 3) {
                const int t = s >> 2;
                const size_t pb = (((size_t)t * 64 + k) * 16 + nb0) * 512 + col;
                *(float2*)(path + pb)        = make_float2(o00, o01);
                *(float2*)(path + pb + 512)  = make_float2(o10, o11);
                *(float2*)(path + pb + 1024) = make_float2(o20, o21);
                *(float2*)(path + pb + 1536) = make_float2(o30, o31);
            }
        }
        __syncthreads();
    }
}

// ---------------------------------------------------------------------------
// z row norms: znorm[t*512+j] = sum_d z[t][j][d]^2. One wave per row.
// ---------------------------------------------------------------------------
__global__ __launch_bounds__(256) void znorm_kernel(const float* __restrict__ z,
                                                    float* __restrict__ znorm)
{
    const int row  = blockIdx.x * 4 + (threadIdx.x >> 6);   // 0..4095
    const int lane = threadIdx.x & 63;
    const float* zr = z + (size_t)row * 512;
    float s = 0.f;
    for (int d = lane; d < 512; d += 64) { float v = zr[d]; s += v * v; }
    #pragma unroll
    for (int off = 32; off > 0; off >>= 1) s += __shfl_down(s, off);
    if (lane == 0) znorm[row] = s;
}

// ---------------------------------------------------------------------------
// G[t][i][j] = sum_d zhat[t][i][d] * z[t][j][d]   (A@B^T, both k-contiguous)
// tile 64x64, BK=64, 256 threads, 4x4 per thread.
// ---------------------------------------------------------------------------
__global__ __launch_bounds__(256) void gemm_kernel(const float* __restrict__ path,
                                                   const float* __restrict__ z,
                                                   float* __restrict__ G)
{
    const int jt = blockIdx.x;   // 0..7
    const int it = blockIdx.y;   // 0..15
    const int t  = blockIdx.z;   // 0..7
    const float* A  = path + (size_t)t * 1024 * 512 + (size_t)it * 64 * 512;
    const float* Bz = z    + (size_t)t * 512 * 512 + (size_t)jt * 64 * 512;
    float* Gp = G + (size_t)t * 1024 * 512 + (size_t)it * 64 * 512 + jt * 64;

    __shared__ float As[64][65];
    __shared__ float Bs[64][65];
    const int tid = threadIdx.x;
    const int tx = tid & 15, ty = tid >> 4;
    const int lr = tid >> 2;
    const int lc = (tid & 3) * 16;

    float acc[4][4] = {};
    for (int kt = 0; kt < 512; kt += 64) {
        #pragma unroll
        for (int u = 0; u < 4; ++u) {
            float4 av = *(const float4*)(A  + (size_t)lr * 512 + kt + lc + u * 4);
            float4 bv = *(const float4*)(Bz + (size_t)lr * 512 + kt + lc + u * 4);
            As[lr][lc + u * 4 + 0] = av.x; As[lr][lc + u * 4 + 1] = av.y;
            As[lr][lc + u * 4 + 2] = av.z; As[lr][lc + u * 4 + 3] = av.w;
            Bs[lr][lc + u * 4 + 0] = bv.x; Bs[lr][lc + u * 4 + 1] = bv.y;
            Bs[lr][lc + u * 4 + 2] = bv.z; Bs[lr][lc + u * 4 + 3] = bv.w;
        }
        __syncthreads();
        #pragma unroll 8
        for (int kk = 0; kk < 64; ++kk) {
            float a0 = As[ty][kk], a1 = As[ty + 16][kk], a2 = As[ty + 32][kk], a3 = As[ty + 48][kk];
            float b0 = Bs[tx][kk], b1 = Bs[tx + 16][kk], b2 = Bs[tx + 32][kk], b3 = Bs[tx + 48][kk];
            acc[0][0] += a0 * b0; acc[0][1] += a0 * b1; acc[0][2] += a0 * b2; acc[0][3] += a0 * b3;
            acc[1][0] += a1 * b0; acc[1][1] += a1 * b1; acc[1][2] += a1 * b2; acc[1][3] += a1 * b3;
            acc[2][0] += a2 * b0; acc[2][1] += a2 * b1; acc[2][2] += a2 * b2; acc[2][3] += a2 * b3;
            acc[3][0] += a3 * b0; acc[3][1] += a3 * b1; acc[3][2] += a3 * b2; acc[3][3] += a3 * b3;
        }
        __syncthreads();
    }
    #pragma unroll
    for (int mi = 0; mi < 4; ++mi)
        #pragma unroll
        for (int mj = 0; mj < 4; ++mj)
            Gp[(size_t)(ty + mi * 16) * 512 + tx + mj * 16] = acc[mi][mj];
}

// ---------------------------------------------------------------------------
// Per (t,i): argmax_j [2G - ||z_j||^2 + (y_j==cls ? 0 : -1e6)], then
// mse partial = sum_d (zhat[i,d] - z[pair,d])^2.  One block per (t,i).
// ---------------------------------------------------------------------------
__global__ __launch_bounds__(256) void pair_mse_kernel(
    const float* __restrict__ G, const float* __restrict__ znorm,
    const int* __restrict__ all_y, const float* __restrict__ path,
    const float* __restrict__ all_z, float* __restrict__ mse_part)
{
    const int t = blockIdx.x >> 10;
    const int i = blockIdx.x & 1023;
    const int cls = i >> 4;              // path_y[i] = i / NB
    const int tid = threadIdx.x;
    const float* Gr = G + ((size_t)t * 1024 + i) * 512;

    float best = -3.4e38f;
    int bestj = 0x7fffffff;
    for (int j = tid; j < 512; j += 256) {
        float sc = 2.f * Gr[j] - znorm[t * 512 + j];
        if (all_y[t * 512 + j] != cls) sc -= 1e6f;
        if (sc > best || (sc == best && j < bestj)) { best = sc; bestj = j; }
    }
    #pragma unroll
    for (int off = 32; off > 0; off >>= 1) {
        float ob = __shfl_down(best, off);
        int   oj = __shfl_down(bestj, off);
        if (ob > best || (ob == best && oj < bestj)) { best = ob; bestj = oj; }
    }
    __shared__ float sb[4];
    __shared__ int   sj[4];
    if ((tid & 63) == 0) { sb[tid >> 6] = best; sj[tid >> 6] = bestj; }
    __syncthreads();
    if (tid == 0) {
        for (int w = 1; w < 4; ++w)
            if (sb[w] > sb[0] || (sb[w] == sb[0] && sj[w] < sj[0])) { sb[0] = sb[w]; sj[0] = sj[w]; }
    }
    __syncthreads();
    const int pair = sj[0];

    const float* zh = path  + ((size_t)t * 1024 + i) * 512;
    const float* zr = all_z + ((size_t)t * 512 + pair) * 512;
    float ssum = 0.f;
    for (int d = tid; d < 512; d += 256) {
        float df = zh[d] - zr[d];
        ssum += df * df;
    }
    #pragma unroll
    for (int off = 32; off > 0; off >>= 1) ssum += __shfl_down(ssum, off);
    __shared__ float sred[4];
    if ((tid & 63) == 0) sred[tid >> 6] = ssum;
    __syncthreads();
    if (tid == 0) mse_part[blockIdx.x] = sred[0] + sred[1] + sred[2] + sred[3];
}

// ---------------------------------------------------------------------------
// CE: per (t, j-tile of 64). allc_j = sum_i e, pos_j = sum_{i: i/16==y_j} e,
// e = (sim<10 ? exp(sim) : 1).  ce_val[t*512+j] = log(allc+eps)-log(pos+eps)
// ---------------------------------------------------------------------------
__global__ __launch_bounds__(256) void ce_kernel(const float* __restrict__ G,
                                                 const int* __restrict__ all_y,
                                                 float* __restrict__ ce_val)
{
    const int t  = blockIdx.x >> 3;
    const int j0 = (blockIdx.x & 7) * 64;
    const int tid = threadIdx.x;
    const int jj = tid & 63, ig = tid >> 6;
    const int j = j0 + jj;
    const int cls = all_y[t * 512 + j];
    const float* Gt = G + (size_t)t * 1024 * 512;

    float alc = 0.f, pos = 0.f;
    for (int i = ig; i < 1024; i += 4) {
        float s = Gt[(size_t)i * 512 + j];
        float e = (s < 10.f) ? expf(s) : 1.f;
        alc += e;
        if ((i >> 4) == cls) pos += e;
    }
    __shared__ float as_[4][64];
    __shared__ float ps_[4][64];
    as_[ig][jj] = alc; ps_[ig][jj] = pos;
    __syncthreads();
    if (tid < 64) {
        float a = as_[0][tid] + as_[1][tid] + as_[2][tid] + as_[3][tid];
        float p = ps_[0][tid] + ps_[1][tid] + ps_[2][tid] + ps_[3][tid];
        ce_val[t * 512 + j0 + tid] = logf(a + 1e-7f) - logf(p + 1e-7f);
    }
}

// ---------------------------------------------------------------------------
// Final deterministic reduction: loss = mean_t( ce_t + mse_t )
// ---------------------------------------------------------------------------
__global__ __launch_bounds__(256) void final_kernel(const float* __restrict__ mse_part,
                                                    const float* __restrict__ ce_val,
                                                    float* __restrict__ out)
{
    const int tid = threadIdx.x;
    float ms = 0.f, cs = 0.f;
    for (int i = tid; i < 8192; i += 256) ms += mse_part[i];
    for (int i = tid; i < 4096; i += 256) cs += ce_val[i];
    #pragma unroll
    for (int off = 32; off > 0; off >>= 1) {
        ms += __shfl_down(ms, off);
        cs += __shfl_down(cs, off);
    }
    __shared__ float mred[4], cred[4];
    if ((tid & 63) == 0) { mred[tid >> 6] = ms; cred[tid >> 6] = cs; }
    __syncthreads();
    if (tid == 0) {
        float M = mred[0] + mred[1] + mred[2] + mred[3];
        float C = cred[0] + cred[1] + cred[2] + cred[3];
        out[0] = C / (8.f * 512.f) + M / (8.f * 1024.f * 512.f);
    }
}

extern "C" void kernel_launch(void* const* d_in, const int* in_sizes, int n_in,
                              void* d_out, int out_size, void* d_ws, size_t ws_size,
                              hipStream_t stream) {
    const float* all_z      = (const float*)d_in[0];
    const int*   all_y      = (const int*)d_in[1];
    const float* init_mu    = (const float*)d_in[2];
    const float* Wf1        = (const float*)d_in[3];
    const float* bf1        = (const float*)d_in[4];
    const float* Wf2        = (const float*)d_in[5];
    const float* bf2        = (const float*)d_in[6];
    const float* Wg1        = (const float*)d_in[7];
    const float* bg1        = (const float*)d_in[8];
    const float* Wg2        = (const float*)d_in[9];
    const float* bg2        = (const float*)d_in[10];
    const float* init_noise = (const float*)d_in[11];
    const float* dW         = (const float*)d_in[12];
    float* out = (float*)d_out;

    float* ws       = (float*)d_ws;
    float* path     = ws;                             // 8*64*16*512 = 4194304 floats
    float* G        = ws + (size_t)4194304;           // 8*1024*512  = 4194304 floats
    float* znorm    = G  + (size_t)4194304;           // 4096
    float* mse_part = znorm + 4096;                   // 8192
    float* ce_val   = mse_part + 8192;                // 4096
    uint4* Wq       = (uint4*)(ce_val + 4096);        // 8388608 uint4 = 128MB

    const size_t need = (size_t)(4194304 + 4194304 + 4096 + 8192 + 4096) * 4
                      + (size_t)8388608 * 16;

    if (ws_size >= need) {
        cvt_kernel<<<8192, 256, 0, stream>>>(Wf1, Wf2, Wg1, Wg2, Wq);
        sde_f16_kernel<<<256, 1024, 0, stream>>>(init_mu, init_noise, Wq,
                                                 bf1, bf2, bg1, bg2, dW, path);
    } else {
        sde_f32_kernel<<<256, 512, 0, stream>>>(init_mu, init_noise,
                                                Wf1, bf1, Wf2, bf2,
                                                Wg1, bg1, Wg2, bg2, dW, path);
    }
    znorm_kernel<<<1024, 256, 0, stream>>>(all_z, znorm);
    gemm_kernel<<<dim3(8, 16, 8), 256, 0, stream>>>(path, all_z, G);
    pair_mse_kernel<<<8192, 256, 0, stream>>>(G, znorm, all_y, path, all_z, mse_part);
    ce_kernel<<<64, 256, 0, stream>>>(G, all_y, ce_val);
    final_kernel<<<1, 256, 0, stream>>>(mse_part, ce_val, out);
}